// Round 7
// baseline (252.563 us; speedup 1.0000x reference)
//
#include <hip/hip_runtime.h>
#include <hip/hip_bf16.h>

#define B_TOT 8192
#define FT    256
#define NREL  4
#define DEG   16

typedef __attribute__((ext_vector_type(8))) short bf16x8;
typedef __attribute__((ext_vector_type(4))) float f32x4;

static __device__ __forceinline__ unsigned short f2bf(float x) {
    union { float f; unsigned int u; } c; c.f = x;
    unsigned int u = c.u;
    u += 0x7fffu + ((u >> 16) & 1u);   // round-to-nearest-even
    return (unsigned short)(u >> 16);
}
static __device__ __forceinline__ float bf2f(unsigned short h) {
    union { unsigned int u; float f; } c; c.u = ((unsigned int)h) << 16;
    return c.f;
}
static __device__ __forceinline__ int pack2(float lo, float hi) {
    return ((int)f2bf(hi) << 16) | (int)f2bf(lo);
}

// ---------- kernel A: features f32 -> bf16 table, 16B stores ----------
__global__ __launch_bounds__(256) void cvt_feat_k(const float* __restrict__ f,
                                                  int* __restrict__ fb,
                                                  int n8) {
    int i = blockIdx.x * 256 + threadIdx.x;
    if (i < n8) {
        float4 a = ((const float4*)f)[i * 2];
        float4 b = ((const float4*)f)[i * 2 + 1];
        int4 o;
        o.x = pack2(a.x, a.y); o.y = pack2(a.z, a.w);
        o.z = pack2(b.x, b.y); o.w = pack2(b.z, b.w);
        ((int4*)fb)[i] = o;
    }
}

// ---------- kernel 0: W [4][f][o] fp32 -> Wt [4][o][f] bf16 (LDS transpose) ----------
__global__ __launch_bounds__(256) void wtrans_k(const float* __restrict__ W,
                                                unsigned short* __restrict__ Wt) {
    __shared__ float t[64][65];   // +1 pad
    int r = blockIdx.z, ft = blockIdx.y, ot = blockIdx.x;
    int c = threadIdx.x & 63, rw = threadIdx.x >> 6;
    const float* src = W + ((size_t)r * 256 + ft * 64) * 256 + ot * 64;
#pragma unroll
    for (int i = 0; i < 16; ++i) {
        int row = i * 4 + rw;
        t[row][c] = src[(size_t)row * 256 + c];       // coalesced over c
    }
    __syncthreads();
    unsigned short* dst = Wt + ((size_t)r * 256 + ot * 64) * 256 + ft * 64;
#pragma unroll
    for (int i = 0; i < 16; ++i) {
        int row = i * 4 + rw;
        dst[(size_t)row * 256 + c] = f2bf(t[c][row]); // coalesced over c
    }
}

// ---------- fused kernel: gather+mean -> LDS -> per-rel GEMM + bias + PReLU + rel-mean ----------
// Block = 16 batch rows. Wave w gathers relation w for all 16 rows into
// A[w][16][264] (bf16, +8 pad). After one sync, each wave computes out
// columns [w*64, w*64+64) for all 16 rows: A from LDS, B-fragments direct
// from global Wt (L2-resident, 0.5 MB), accumulate over relations.
__global__ __launch_bounds__(256) void fused_k(const unsigned short* __restrict__ fb,
                                               const int* __restrict__ nidx,
                                               const unsigned short* __restrict__ Wt,
                                               const float* __restrict__ bias,
                                               const float* __restrict__ prelu,
                                               float* __restrict__ out) {
    __shared__ unsigned short A[NREL][16][264];
    int tid = threadIdx.x, lane = tid & 63, w = tid >> 6;
    int blk = blockIdx.x;

    // ---- phase 1: gather + mean (relation = w) ----
    for (int j = 0; j < 16; ++j) {
        int b = blk * 16 + j;
        const int* idx = nidx + ((size_t)b * NREL + w) * DEG;
        int4 i0 = *(const int4*)(idx);
        int4 i1 = *(const int4*)(idx + 4);
        int4 i2 = *(const int4*)(idx + 8);
        int4 i3 = *(const int4*)(idx + 12);
        float s0 = 0.f, s1 = 0.f, s2 = 0.f, s3 = 0.f;
#define ACC(nn) { const ushort4 x = ((const ushort4*)(fb + (size_t)(nn) * FT))[lane]; \
                  s0 += bf2f(x.x); s1 += bf2f(x.y); s2 += bf2f(x.z); s3 += bf2f(x.w); }
        ACC(i0.x) ACC(i0.y) ACC(i0.z) ACC(i0.w)
        ACC(i1.x) ACC(i1.y) ACC(i1.z) ACC(i1.w)
        ACC(i2.x) ACC(i2.y) ACC(i2.z) ACC(i2.w)
        ACC(i3.x) ACC(i3.y) ACC(i3.z) ACC(i3.w)
#undef ACC
        const float inv = 1.0f / 16.0f;
        ushort4 o;
        o.x = f2bf(s0 * inv); o.y = f2bf(s1 * inv);
        o.z = f2bf(s2 * inv); o.w = f2bf(s3 * inv);
        *(ushort4*)(&A[w][j][lane * 4]) = o;
    }
    __syncthreads();

    // ---- phase 2: GEMM over 4 relations, fused epilogue ----
    int mrow = lane & 15, quad = lane >> 4;
    float pa = prelu[0];
    f32x4 accO[4] = {};
#pragma unroll
    for (int r = 0; r < NREL; ++r) {
        f32x4 acc[4] = {};
#pragma unroll
        for (int kk = 0; kk < 8; ++kk) {
            int k0 = kk * 32 + quad * 8;
            bf16x8 a = *(const bf16x8*)&A[r][mrow][k0];
#pragma unroll
            for (int nt = 0; nt < 4; ++nt) {
                int n = w * 64 + nt * 16 + mrow;
                bf16x8 bf = *(const bf16x8*)(Wt + ((size_t)(r * 256 + n)) * 256 + k0);
                acc[nt] = __builtin_amdgcn_mfma_f32_16x16x32_bf16(a, bf, acc[nt], 0, 0, 0);
            }
        }
#pragma unroll
        for (int nt = 0; nt < 4; ++nt) {
            float bv = bias[r * 256 + w * 64 + nt * 16 + mrow];
#pragma unroll
            for (int i = 0; i < 4; ++i) {
                float h = acc[nt][i] + bv;
                h = (h >= 0.f) ? h : pa * h;
                accO[nt][i] += h;
            }
        }
    }
    // C/D layout: col = lane&15 (within n-tile), row = quad*4 + i
#pragma unroll
    for (int nt = 0; nt < 4; ++nt) {
        int ocol = w * 64 + nt * 16 + mrow;
#pragma unroll
        for (int i = 0; i < 4; ++i) {
            int row = blk * 16 + quad * 4 + i;
            out[(size_t)row * 256 + ocol] = accO[nt][i] * 0.25f;
        }
    }
}

// ---------- fallback kernels (ws too small for bf16 table) ----------
__global__ __launch_bounds__(256) void gather_mean_k(const float* __restrict__ feat,
                                                     const int* __restrict__ nidx,
                                                     unsigned short* __restrict__ v) {
    int wave = threadIdx.x >> 6;
    int lane = threadIdx.x & 63;
    int task = blockIdx.x * 4 + wave;
    int b = task >> 2, r = task & 3;
    const int* idx = nidx + ((size_t)b * NREL + r) * DEG;
    int4 i0 = *(const int4*)(idx);
    int4 i1 = *(const int4*)(idx + 4);
    int4 i2 = *(const int4*)(idx + 8);
    int4 i3 = *(const int4*)(idx + 12);
    float4 s = make_float4(0.f, 0.f, 0.f, 0.f);
#define ACC(nn) { const float4 x = ((const float4*)(feat + (size_t)(nn) * FT))[lane]; \
                  s.x += x.x; s.y += x.y; s.z += x.z; s.w += x.w; }
    ACC(i0.x) ACC(i0.y) ACC(i0.z) ACC(i0.w)
    ACC(i1.x) ACC(i1.y) ACC(i1.z) ACC(i1.w)
    ACC(i2.x) ACC(i2.y) ACC(i2.z) ACC(i2.w)
    ACC(i3.x) ACC(i3.y) ACC(i3.z) ACC(i3.w)
#undef ACC
    const float inv = 1.0f / 16.0f;
    ushort4 o;
    o.x = f2bf(s.x * inv); o.y = f2bf(s.y * inv);
    o.z = f2bf(s.z * inv); o.w = f2bf(s.w * inv);
    *(ushort4*)(v + ((size_t)r * B_TOT + b) * FT + 4 * lane) = o;
}

__global__ __launch_bounds__(256) void gemm_k(const unsigned short* __restrict__ v,
                                              const unsigned short* __restrict__ Wt,
                                              const float* __restrict__ bias,
                                              const float* __restrict__ prelu,
                                              float* __restrict__ out) {
    __shared__ unsigned short As[64][264];
    __shared__ unsigned short Bs[64][264];
    int tid  = threadIdx.x;
    int lane = tid & 63, w = tid >> 6;
    int wm = w >> 1, wn = w & 1;
    int mrow = lane & 15, quad = lane >> 4;
    int bid = blockIdx.x;
    int m0 = (bid & 127) * 64, n0 = (bid >> 7) * 64;
    float pa = prelu[0];

    f32x4 accO[2][2] = {};
    int ocol0 = n0 + wn * 32 + mrow;

    for (int r = 0; r < NREL; ++r) {
        const unsigned short* Ag = v  + ((size_t)r * B_TOT + m0) * FT;
        const unsigned short* Bg = Wt + ((size_t)r * 256  + n0) * FT;
#pragma unroll
        for (int i = 0; i < 8; ++i) {
            int u = tid + i * 256;
            int row = u >> 5, c8 = (u & 31) * 8;
            *(int4*)(&As[row][c8]) = *(const int4*)(Ag + row * FT + c8);
            *(int4*)(&Bs[row][c8]) = *(const int4*)(Bg + row * FT + c8);
        }
        __syncthreads();

        f32x4 acc[2][2] = {};
#pragma unroll
        for (int kk = 0; kk < 8; ++kk) {
            int k0 = kk * 32 + quad * 8;
            bf16x8 a0 = *(const bf16x8*)&As[wm * 32 + mrow][k0];
            bf16x8 a1 = *(const bf16x8*)&As[wm * 32 + 16 + mrow][k0];
            bf16x8 b0 = *(const bf16x8*)&Bs[wn * 32 + mrow][k0];
            bf16x8 b1 = *(const bf16x8*)&Bs[wn * 32 + 16 + mrow][k0];
            acc[0][0] = __builtin_amdgcn_mfma_f32_16x16x32_bf16(a0, b0, acc[0][0], 0, 0, 0);
            acc[1][0] = __builtin_amdgcn_mfma_f32_16x16x32_bf16(a1, b0, acc[1][0], 0, 0, 0);
            acc[0][1] = __builtin_amdgcn_mfma_f32_16x16x32_bf16(a0, b1, acc[0][1], 0, 0, 0);
            acc[1][1] = __builtin_amdgcn_mfma_f32_16x16x32_bf16(a1, b1, acc[1][1], 0, 0, 0);
        }
        __syncthreads();

        float b0v = bias[r * 256 + ocol0];
        float b1v = bias[r * 256 + ocol0 + 16];
#pragma unroll
        for (int mt = 0; mt < 2; ++mt)
#pragma unroll
            for (int i = 0; i < 4; ++i) {
                float h0 = acc[mt][0][i] + b0v; h0 = (h0 >= 0.f) ? h0 : pa * h0;
                float h1 = acc[mt][1][i] + b1v; h1 = (h1 >= 0.f) ? h1 : pa * h1;
                accO[mt][0][i] += h0;
                accO[mt][1][i] += h1;
            }
    }

#pragma unroll
    for (int mt = 0; mt < 2; ++mt)
#pragma unroll
        for (int i = 0; i < 4; ++i) {
            int row = m0 + wm * 32 + mt * 16 + quad * 4 + i;
            out[(size_t)row * 256 + ocol0]      = accO[mt][0][i] * 0.25f;
            out[(size_t)row * 256 + ocol0 + 16] = accO[mt][1][i] * 0.25f;
        }
}

extern "C" void kernel_launch(void* const* d_in, const int* in_sizes, int n_in,
                              void* d_out, int out_size, void* d_ws, size_t ws_size,
                              hipStream_t stream) {
    const float* feat  = (const float*)d_in[0];   // [100000,256] f32
    const int*   nidx  = (const int*)  d_in[1];   // [8192,4,16] i32
    const float* W     = (const float*)d_in[2];   // [4,256,256] f32
    const float* bias  = (const float*)d_in[3];   // [4,256] f32
    const float* prelu = (const float*)d_in[4];   // [1] f32
    float* out = (float*)d_out;                   // [8192,256] f32

    const size_t feat_elems = (size_t)in_sizes[0];          // 25,600,000
    const size_t fb_bytes = feat_elems * 2;                 // 51.2 MB
    const size_t wt_bytes = (size_t)NREL * 256 * FT * 2;    // 0.5 MB
    const size_t v_bytes  = (size_t)NREL * B_TOT * FT * 2;  // 16.78 MB

    if (ws_size >= fb_bytes + wt_bytes) {
        unsigned short* fb = (unsigned short*)d_ws;
        unsigned short* Wt = fb + feat_elems;
        int n8 = (int)(feat_elems / 8);
        cvt_feat_k<<<(n8 + 255) / 256, 256, 0, stream>>>(feat, (int*)fb, n8);
        wtrans_k<<<dim3(4, 4, 4), 256, 0, stream>>>(W, Wt);
        fused_k<<<B_TOT / 16, 256, 0, stream>>>(fb, nidx, Wt, bias, prelu, out);
    } else {
        unsigned short* v  = (unsigned short*)d_ws;
        unsigned short* Wt = v + (size_t)NREL * B_TOT * FT;
        (void)v_bytes;
        wtrans_k<<<dim3(4, 4, 4), 256, 0, stream>>>(W, Wt);
        gather_mean_k<<<B_TOT, 256, 0, stream>>>(feat, nidx, v);
        gemm_k<<<512, 256, 0, stream>>>(v, Wt, bias, prelu, out);
    }
}

// Round 8
// 231.546 us; speedup vs baseline: 1.0908x; 1.0908x over previous
//
#include <hip/hip_runtime.h>
#include <hip/hip_bf16.h>

#define B_TOT 8192
#define FT    256
#define NREL  4
#define DEG   16

typedef __attribute__((ext_vector_type(8))) short bf16x8;
typedef __attribute__((ext_vector_type(4))) float f32x4;

static __device__ __forceinline__ unsigned short f2bf(float x) {
    union { float f; unsigned int u; } c; c.f = x;
    unsigned int u = c.u;
    u += 0x7fffu + ((u >> 16) & 1u);   // round-to-nearest-even
    return (unsigned short)(u >> 16);
}
static __device__ __forceinline__ float bf2f(unsigned short h) {
    union { unsigned int u; float f; } c; c.u = ((unsigned int)h) << 16;
    return c.f;
}
static __device__ __forceinline__ int pack2(float lo, float hi) {
    return ((int)f2bf(hi) << 16) | (int)f2bf(lo);
}

// ---------- kernel A: features f32 -> bf16 table, 16B stores ----------
__global__ __launch_bounds__(256) void cvt_feat_k(const float* __restrict__ f,
                                                  int* __restrict__ fb,
                                                  int n8) {
    int i = blockIdx.x * 256 + threadIdx.x;
    if (i < n8) {
        float4 a = ((const float4*)f)[i * 2];
        float4 b = ((const float4*)f)[i * 2 + 1];
        int4 o;
        o.x = pack2(a.x, a.y); o.y = pack2(a.z, a.w);
        o.z = pack2(b.x, b.y); o.w = pack2(b.z, b.w);
        ((int4*)fb)[i] = o;
    }
}

// ---------- kernel 0: W [4][f][o] fp32 -> Wt [4][o][f] bf16 (LDS transpose) ----------
__global__ __launch_bounds__(256) void wtrans_k(const float* __restrict__ W,
                                                unsigned short* __restrict__ Wt) {
    __shared__ float t[64][65];   // +1 pad
    int r = blockIdx.z, ft = blockIdx.y, ot = blockIdx.x;
    int c = threadIdx.x & 63, rw = threadIdx.x >> 6;
    const float* src = W + ((size_t)r * 256 + ft * 64) * 256 + ot * 64;
#pragma unroll
    for (int i = 0; i < 16; ++i) {
        int row = i * 4 + rw;
        t[row][c] = src[(size_t)row * 256 + c];       // coalesced over c
    }
    __syncthreads();
    unsigned short* dst = Wt + ((size_t)r * 256 + ot * 64) * 256 + ft * 64;
#pragma unroll
    for (int i = 0; i < 16; ++i) {
        int row = i * 4 + rw;
        dst[(size_t)row * 256 + c] = f2bf(t[c][row]); // coalesced over c
    }
}

// ---------- fused kernel v2: 1024 threads / 16 waves per block ----------
// Block = 16 batch rows, grid 512 -> 2 blocks/CU, 32 waves/CU (full thread
// occupancy; R6's 4-wave version sat at 8 waves/CU and was gather-latency
// bound at 1.5 TB/s). Phase 1: wave wv gathers all 4 relations of row wv
// into A[r][wv][.]. Phase 2: wave wv computes output n-tile wv (16 cols)
// for all 16 rows; A-frags from LDS, B-frags direct from L2-resident Wt.
__global__ __launch_bounds__(1024) void fused_k(const unsigned short* __restrict__ fb,
                                                const int* __restrict__ nidx,
                                                const unsigned short* __restrict__ Wt,
                                                const float* __restrict__ bias,
                                                const float* __restrict__ prelu,
                                                float* __restrict__ out) {
    __shared__ unsigned short A[NREL][16][264];   // +8 pad (conflicts measured negligible)
    int tid = threadIdx.x, lane = tid & 63, wv = tid >> 6;
    int blk = blockIdx.x;
    int b = blk * 16 + wv;

    // ---- phase 1: gather + mean; wave wv owns row wv, all relations ----
    const int* idxb = nidx + (size_t)b * NREL * DEG;
#pragma unroll
    for (int r = 0; r < NREL; ++r) {
        const int* idx = idxb + r * DEG;
        int4 i0 = *(const int4*)(idx);
        int4 i1 = *(const int4*)(idx + 4);
        int4 i2 = *(const int4*)(idx + 8);
        int4 i3 = *(const int4*)(idx + 12);
        float s0 = 0.f, s1 = 0.f, s2 = 0.f, s3 = 0.f;
#define ACC(nn) { const ushort4 x = ((const ushort4*)(fb + (size_t)(nn) * FT))[lane]; \
                  s0 += bf2f(x.x); s1 += bf2f(x.y); s2 += bf2f(x.z); s3 += bf2f(x.w); }
        ACC(i0.x) ACC(i0.y) ACC(i0.z) ACC(i0.w)
        ACC(i1.x) ACC(i1.y) ACC(i1.z) ACC(i1.w)
        ACC(i2.x) ACC(i2.y) ACC(i2.z) ACC(i2.w)
        ACC(i3.x) ACC(i3.y) ACC(i3.z) ACC(i3.w)
#undef ACC
        const float inv = 1.0f / 16.0f;
        ushort4 o;
        o.x = f2bf(s0 * inv); o.y = f2bf(s1 * inv);
        o.z = f2bf(s2 * inv); o.w = f2bf(s3 * inv);
        *(ushort4*)(&A[r][wv][lane * 4]) = o;
    }
    __syncthreads();

    // ---- phase 2: wave wv -> output cols [wv*16, wv*16+16) ----
    int mrow = lane & 15, quad = lane >> 4;
    float pa = prelu[0];
    int n = wv * 16 + mrow;
    f32x4 accO = {};
#pragma unroll
    for (int r = 0; r < NREL; ++r) {
        f32x4 acc = {};
        const unsigned short* Bg = Wt + ((size_t)(r * 256 + n)) * 256;
#pragma unroll
        for (int kk = 0; kk < 8; ++kk) {
            int k0 = kk * 32 + quad * 8;
            bf16x8 a  = *(const bf16x8*)&A[r][mrow][k0];
            bf16x8 bf = *(const bf16x8*)(Bg + k0);
            acc = __builtin_amdgcn_mfma_f32_16x16x32_bf16(a, bf, acc, 0, 0, 0);
        }
        float bv = bias[r * 256 + n];
#pragma unroll
        for (int i = 0; i < 4; ++i) {
            float h = acc[i] + bv;
            h = (h >= 0.f) ? h : pa * h;
            accO[i] += h;
        }
    }
    // C/D layout: col = lane&15, row = quad*4 + i
#pragma unroll
    for (int i = 0; i < 4; ++i) {
        int row = blk * 16 + quad * 4 + i;
        out[(size_t)row * 256 + n] = accO[i] * 0.25f;
    }
}

// ---------- fallback kernels (ws too small for bf16 table) ----------
__global__ __launch_bounds__(256) void gather_mean_k(const float* __restrict__ feat,
                                                     const int* __restrict__ nidx,
                                                     unsigned short* __restrict__ v) {
    int wave = threadIdx.x >> 6;
    int lane = threadIdx.x & 63;
    int task = blockIdx.x * 4 + wave;
    int b = task >> 2, r = task & 3;
    const int* idx = nidx + ((size_t)b * NREL + r) * DEG;
    int4 i0 = *(const int4*)(idx);
    int4 i1 = *(const int4*)(idx + 4);
    int4 i2 = *(const int4*)(idx + 8);
    int4 i3 = *(const int4*)(idx + 12);
    float4 s = make_float4(0.f, 0.f, 0.f, 0.f);
#define ACC(nn) { const float4 x = ((const float4*)(feat + (size_t)(nn) * FT))[lane]; \
                  s.x += x.x; s.y += x.y; s.z += x.z; s.w += x.w; }
    ACC(i0.x) ACC(i0.y) ACC(i0.z) ACC(i0.w)
    ACC(i1.x) ACC(i1.y) ACC(i1.z) ACC(i1.w)
    ACC(i2.x) ACC(i2.y) ACC(i2.z) ACC(i2.w)
    ACC(i3.x) ACC(i3.y) ACC(i3.z) ACC(i3.w)
#undef ACC
    const float inv = 1.0f / 16.0f;
    ushort4 o;
    o.x = f2bf(s.x * inv); o.y = f2bf(s.y * inv);
    o.z = f2bf(s.z * inv); o.w = f2bf(s.w * inv);
    *(ushort4*)(v + ((size_t)r * B_TOT + b) * FT + 4 * lane) = o;
}

__global__ __launch_bounds__(256) void gemm_k(const unsigned short* __restrict__ v,
                                              const unsigned short* __restrict__ Wt,
                                              const float* __restrict__ bias,
                                              const float* __restrict__ prelu,
                                              float* __restrict__ out) {
    __shared__ unsigned short As[64][264];
    __shared__ unsigned short Bs[64][264];
    int tid  = threadIdx.x;
    int lane = tid & 63, w = tid >> 6;
    int wm = w >> 1, wn = w & 1;
    int mrow = lane & 15, quad = lane >> 4;
    int bid = blockIdx.x;
    int m0 = (bid & 127) * 64, n0 = (bid >> 7) * 64;
    float pa = prelu[0];

    f32x4 accO[2][2] = {};
    int ocol0 = n0 + wn * 32 + mrow;

    for (int r = 0; r < NREL; ++r) {
        const unsigned short* Ag = v  + ((size_t)r * B_TOT + m0) * FT;
        const unsigned short* Bg = Wt + ((size_t)r * 256  + n0) * FT;
#pragma unroll
        for (int i = 0; i < 8; ++i) {
            int u = tid + i * 256;
            int row = u >> 5, c8 = (u & 31) * 8;
            *(int4*)(&As[row][c8]) = *(const int4*)(Ag + row * FT + c8);
            *(int4*)(&Bs[row][c8]) = *(const int4*)(Bg + row * FT + c8);
        }
        __syncthreads();

        f32x4 acc[2][2] = {};
#pragma unroll
        for (int kk = 0; kk < 8; ++kk) {
            int k0 = kk * 32 + quad * 8;
            bf16x8 a0 = *(const bf16x8*)&As[wm * 32 + mrow][k0];
            bf16x8 a1 = *(const bf16x8*)&As[wm * 32 + 16 + mrow][k0];
            bf16x8 b0 = *(const bf16x8*)&Bs[wn * 32 + mrow][k0];
            bf16x8 b1 = *(const bf16x8*)&Bs[wn * 32 + 16 + mrow][k0];
            acc[0][0] = __builtin_amdgcn_mfma_f32_16x16x32_bf16(a0, b0, acc[0][0], 0, 0, 0);
            acc[1][0] = __builtin_amdgcn_mfma_f32_16x16x32_bf16(a1, b0, acc[1][0], 0, 0, 0);
            acc[0][1] = __builtin_amdgcn_mfma_f32_16x16x32_bf16(a0, b1, acc[0][1], 0, 0, 0);
            acc[1][1] = __builtin_amdgcn_mfma_f32_16x16x32_bf16(a1, b1, acc[1][1], 0, 0, 0);
        }
        __syncthreads();

        float b0v = bias[r * 256 + ocol0];
        float b1v = bias[r * 256 + ocol0 + 16];
#pragma unroll
        for (int mt = 0; mt < 2; ++mt)
#pragma unroll
            for (int i = 0; i < 4; ++i) {
                float h0 = acc[mt][0][i] + b0v; h0 = (h0 >= 0.f) ? h0 : pa * h0;
                float h1 = acc[mt][1][i] + b1v; h1 = (h1 >= 0.f) ? h1 : pa * h1;
                accO[mt][0][i] += h0;
                accO[mt][1][i] += h1;
            }
    }

#pragma unroll
    for (int mt = 0; mt < 2; ++mt)
#pragma unroll
        for (int i = 0; i < 4; ++i) {
            int row = m0 + wm * 32 + mt * 16 + quad * 4 + i;
            out[(size_t)row * 256 + ocol0]      = accO[mt][0][i] * 0.25f;
            out[(size_t)row * 256 + ocol0 + 16] = accO[mt][1][i] * 0.25f;
        }
}

extern "C" void kernel_launch(void* const* d_in, const int* in_sizes, int n_in,
                              void* d_out, int out_size, void* d_ws, size_t ws_size,
                              hipStream_t stream) {
    const float* feat  = (const float*)d_in[0];   // [100000,256] f32
    const int*   nidx  = (const int*)  d_in[1];   // [8192,4,16] i32
    const float* W     = (const float*)d_in[2];   // [4,256,256] f32
    const float* bias  = (const float*)d_in[3];   // [4,256] f32
    const float* prelu = (const float*)d_in[4];   // [1] f32
    float* out = (float*)d_out;                   // [8192,256] f32

    const size_t feat_elems = (size_t)in_sizes[0];          // 25,600,000
    const size_t fb_bytes = feat_elems * 2;                 // 51.2 MB
    const size_t wt_bytes = (size_t)NREL * 256 * FT * 2;    // 0.5 MB

    if (ws_size >= fb_bytes + wt_bytes) {
        unsigned short* fb = (unsigned short*)d_ws;
        unsigned short* Wt = fb + feat_elems;
        int n8 = (int)(feat_elems / 8);
        cvt_feat_k<<<(n8 + 255) / 256, 256, 0, stream>>>(feat, (int*)fb, n8);
        wtrans_k<<<dim3(4, 4, 4), 256, 0, stream>>>(W, Wt);
        fused_k<<<B_TOT / 16, 1024, 0, stream>>>(fb, nidx, Wt, bias, prelu, out);
    } else {
        unsigned short* v  = (unsigned short*)d_ws;
        unsigned short* Wt = v + (size_t)NREL * B_TOT * FT;
        wtrans_k<<<dim3(4, 4, 4), 256, 0, stream>>>(W, Wt);
        gather_mean_k<<<B_TOT, 256, 0, stream>>>(feat, nidx, v);
        gemm_k<<<512, 256, 0, stream>>>(v, Wt, bias, prelu, out);
    }
}